// Round 1
// baseline (30483.679 us; speedup 1.0000x reference)
//
#include <hip/hip_runtime.h>
#include <hip/hip_bf16.h>
#include <math.h>

#define E_ 512
#define H_ 8
#define NL_ 6
#define F_ 1024
#define S_ 512
#define L_ 513
#define B_ 32
#define DH_ 64
#define M_ (B_*L_)   // 16416
#define EPS_ 1e-5f

// ---------------- block reduce helpers (blockDim.x == 256, 4 waves) -------
__device__ __forceinline__ float blk_max(float v, float* red) {
  #pragma unroll
  for (int off = 32; off > 0; off >>= 1) v = fmaxf(v, __shfl_down(v, off));
  int wid = threadIdx.x >> 6;
  if ((threadIdx.x & 63) == 0) red[wid] = v;
  __syncthreads();
  if (threadIdx.x == 0) {
    red[0] = fmaxf(fmaxf(red[0], red[1]), fmaxf(red[2], red[3]));
  }
  __syncthreads();
  float r = red[0];
  __syncthreads();
  return r;
}

__device__ __forceinline__ float blk_sum(float v, float* red) {
  #pragma unroll
  for (int off = 32; off > 0; off >>= 1) v += __shfl_down(v, off);
  int wid = threadIdx.x >> 6;
  if ((threadIdx.x & 63) == 0) red[wid] = v;
  __syncthreads();
  if (threadIdx.x == 0) {
    red[0] = (red[0] + red[1]) + (red[2] + red[3]);
  }
  __syncthreads();
  float r = red[0];
  __syncthreads();
  return r;
}

// ---------------- embed: src = tok_w * x_num + tok_b ----------------------
__global__ __launch_bounds__(256) void k_embed(
    const float* __restrict__ x, const float* __restrict__ tok_w,
    const float* __restrict__ tok_b, float* __restrict__ src) {
  int idx = blockIdx.x * 256 + threadIdx.x;
  if (idx >= B_ * L_ * E_) return;
  int e  = idx & (E_ - 1);
  int bl = idx >> 9;          // E_ = 512
  int l  = bl % L_;
  int b  = bl / L_;
  float xv = (l == 0) ? 1.0f : x[b * S_ + (l - 1)];
  src[idx] = tok_w[l * E_ + e] * xv + tok_b[l * E_ + e];
}

// ---------------- C = A @ W^T + bias (optionally relu) --------------------
// A: MxK row-major, W: NxK row-major, C: MxN. K % 16 == 0, N % 64 == 0.
__global__ __launch_bounds__(256) void k_gemm_nt(
    const float* __restrict__ A, const float* __restrict__ W,
    const float* __restrict__ bias, float* __restrict__ C,
    int M, int N, int K, int relu) {
  __shared__ float As[16][64];
  __shared__ float Ws[16][64];
  int m0 = blockIdx.x * 64, n0 = blockIdx.y * 64;
  int t = threadIdx.x;
  int tx = t & 15, ty = t >> 4;
  float acc[4][4] = {};
  for (int kt = 0; kt < K; kt += 16) {
    #pragma unroll
    for (int i = 0; i < 4; ++i) {
      int lin = t + i * 256;
      int kk = lin & 15, mm = lin >> 4;
      int gm = m0 + mm;
      As[kk][mm] = (gm < M) ? A[(size_t)gm * K + kt + kk] : 0.0f;
      Ws[kk][mm] = W[(size_t)(n0 + mm) * K + kt + kk];
    }
    __syncthreads();
    #pragma unroll
    for (int kk = 0; kk < 16; ++kk) {
      float a[4], w[4];
      #pragma unroll
      for (int i = 0; i < 4; ++i) a[i] = As[kk][ty * 4 + i];
      #pragma unroll
      for (int j = 0; j < 4; ++j) w[j] = Ws[kk][tx * 4 + j];
      #pragma unroll
      for (int i = 0; i < 4; ++i)
        #pragma unroll
        for (int j = 0; j < 4; ++j) acc[i][j] += a[i] * w[j];
    }
    __syncthreads();
  }
  #pragma unroll
  for (int i = 0; i < 4; ++i) {
    int gm = m0 + ty * 4 + i;
    if (gm >= M) continue;
    #pragma unroll
    for (int j = 0; j < 4; ++j) {
      int gn = n0 + tx * 4 + j;
      float v = acc[i][j] + bias[gn];
      if (relu) v = fmaxf(v, 0.0f);
      C[(size_t)gm * N + gn] = v;
    }
  }
}

// ---------------- batched C[b] = A[b] @ B[b] ------------------------------
// A: MxK, B: KxN, C: MxN per batch. N % 64 == 0; M, K arbitrary.
__global__ __launch_bounds__(256) void k_gemm_nn_b(
    const float* __restrict__ Ag, const float* __restrict__ Bg,
    float* __restrict__ Cg, int M, int N, int K) {
  const float* A  = Ag + (size_t)blockIdx.z * M * K;
  const float* Bp = Bg + (size_t)blockIdx.z * K * N;
  float*       C  = Cg + (size_t)blockIdx.z * M * N;
  __shared__ float As[16][64];
  __shared__ float Bs[16][64];
  int m0 = blockIdx.x * 64, n0 = blockIdx.y * 64;
  int t = threadIdx.x;
  int tx = t & 15, ty = t >> 4;
  float acc[4][4] = {};
  for (int kt = 0; kt < K; kt += 16) {
    #pragma unroll
    for (int i = 0; i < 4; ++i) {
      int lin = t + i * 256;
      int kk = lin & 15, mm = lin >> 4;
      int gm = m0 + mm;
      As[kk][mm] = (gm < M && kt + kk < K) ? A[(size_t)gm * K + kt + kk] : 0.0f;
      int kk2 = lin >> 6, nn = lin & 63;
      Bs[kk2][nn] = (kt + kk2 < K) ? Bp[(size_t)(kt + kk2) * N + n0 + nn] : 0.0f;
    }
    __syncthreads();
    #pragma unroll
    for (int kk = 0; kk < 16; ++kk) {
      float a[4], w[4];
      #pragma unroll
      for (int i = 0; i < 4; ++i) a[i] = As[kk][ty * 4 + i];
      #pragma unroll
      for (int j = 0; j < 4; ++j) w[j] = Bs[kk][tx * 4 + j];
      #pragma unroll
      for (int i = 0; i < 4; ++i)
        #pragma unroll
        for (int j = 0; j < 4; ++j) acc[i][j] += a[i] * w[j];
    }
    __syncthreads();
  }
  #pragma unroll
  for (int i = 0; i < 4; ++i) {
    int gm = m0 + ty * 4 + i;
    if (gm >= M) continue;
    #pragma unroll
    for (int j = 0; j < 4; ++j) {
      int gn = n0 + tx * 4 + j;
      C[(size_t)gm * N + gn] = acc[i][j];
    }
  }
}

// ---------------- fused attention probability kernel ----------------------
// One block per (l, b). Computes, for row l of batch b:
//   per-head softmax over m of (q . k * scale), averaged over heads,
//   + bias, second softmax -> W2[b, l, :]
__global__ __launch_bounds__(256) void k_attn(
    const float* __restrict__ Q, const float* __restrict__ Kb,
    const float* __restrict__ bias, float* __restrict__ W2) {
  int l = blockIdx.x, b = blockIdx.y;
  int t = threadIdx.x;
  __shared__ float qs[DH_];
  __shared__ float red[4];
  const float scale = 0.125f;  // 1/sqrt(64)
  float avg[3] = {0.f, 0.f, 0.f};
  int   mv[3]  = { t, t + 256, t + 512 };
  bool  valid3 = (t + 512 < L_);
  const float* qrow = Q + ((size_t)b * L_ + l) * E_;
  const float* kbase = Kb + (size_t)b * L_ * E_;

  for (int h = 0; h < H_; ++h) {
    __syncthreads();
    if (t < DH_) qs[t] = qrow[h * DH_ + t];
    __syncthreads();
    float s[3];
    float lmax = -INFINITY;
    #pragma unroll
    for (int i = 0; i < 3; ++i) {
      if (i == 2 && !valid3) { s[i] = -INFINITY; continue; }
      const float* kr = kbase + (size_t)mv[i] * E_ + h * DH_;
      float d = 0.f;
      #pragma unroll
      for (int dd = 0; dd < DH_; ++dd) d += qs[dd] * kr[dd];
      s[i] = d * scale;
      lmax = fmaxf(lmax, s[i]);
    }
    float rmax = blk_max(lmax, red);
    float e[3];
    float lsum = 0.f;
    #pragma unroll
    for (int i = 0; i < 3; ++i) {
      e[i] = (i == 2 && !valid3) ? 0.f : __expf(s[i] - rmax);
      lsum += e[i];
    }
    float rsum = blk_sum(lsum, red);
    float inv = 1.0f / rsum;
    #pragma unroll
    for (int i = 0; i < 3; ++i) avg[i] += e[i] * inv;
  }

  // second softmax over (avg/H + bias[l, m])
  float v[3];
  float lmax = -INFINITY;
  #pragma unroll
  for (int i = 0; i < 3; ++i) {
    if (i == 2 && !valid3) { v[i] = -INFINITY; continue; }
    v[i] = avg[i] * (1.0f / H_) + bias[(size_t)l * L_ + mv[i]];
    lmax = fmaxf(lmax, v[i]);
  }
  float rmax = blk_max(lmax, red);
  float e[3];
  float lsum = 0.f;
  #pragma unroll
  for (int i = 0; i < 3; ++i) {
    e[i] = (i == 2 && !valid3) ? 0.f : __expf(v[i] - rmax);
    lsum += e[i];
  }
  float rsum = blk_sum(lsum, red);
  float inv = 1.0f / rsum;
  float* w2row = W2 + ((size_t)b * L_ + l) * L_;
  #pragma unroll
  for (int i = 0; i < 3; ++i) {
    if (i == 2 && !valid3) continue;
    w2row[mv[i]] = e[i] * inv;
  }
}

// ---------------- out = LayerNorm(x + y) * w + b, row-wise over E ---------
__global__ __launch_bounds__(256) void k_add_ln(
    const float* __restrict__ X, const float* __restrict__ Y,
    const float* __restrict__ w, const float* __restrict__ bb,
    float* __restrict__ out) {
  int row = blockIdx.x;
  int t = threadIdx.x;
  const float* xr = X + (size_t)row * E_;
  const float* yr = Y + (size_t)row * E_;
  __shared__ float red[4];
  float v0 = xr[t] + yr[t];
  float v1 = xr[t + 256] + yr[t + 256];
  float mean = blk_sum(v0 + v1, red) * (1.0f / E_);
  float d0 = v0 - mean, d1 = v1 - mean;
  float var = blk_sum(d0 * d0 + d1 * d1, red) * (1.0f / E_);
  float inv = rsqrtf(var + EPS_);
  float* orow = out + (size_t)row * E_;
  orow[t]       = d0 * inv * w[t]       + bb[t];
  orow[t + 256] = d1 * inv * w[t + 256] + bb[t + 256];
}

// ---------------- extract out = src[:, 0, :] ------------------------------
__global__ __launch_bounds__(256) void k_extract(
    const float* __restrict__ src, float* __restrict__ out) {
  int i = blockIdx.x * 256 + threadIdx.x;
  if (i >= B_ * E_) return;
  int b = i >> 9, e = i & (E_ - 1);
  out[i] = src[((size_t)b * L_) * E_ + e];
}

extern "C" void kernel_launch(void* const* d_in, const int* in_sizes, int n_in,
                              void* d_out, int out_size, void* d_ws, size_t ws_size,
                              hipStream_t stream) {
  const float* x        = (const float*)d_in[0];
  const float* tok_w    = (const float*)d_in[1];
  const float* tok_b    = (const float*)d_in[2];
  const float* bias     = (const float*)d_in[3];
  const float* in_proj_w= (const float*)d_in[4];
  const float* in_proj_b= (const float*)d_in[5];
  const float* fc1_w    = (const float*)d_in[6];
  const float* fc1_b    = (const float*)d_in[7];
  const float* fc2_w    = (const float*)d_in[8];
  const float* fc2_b    = (const float*)d_in[9];
  const float* ln1_w    = (const float*)d_in[10];
  const float* ln1_b    = (const float*)d_in[11];
  const float* ln2_w    = (const float*)d_in[12];
  const float* ln2_b    = (const float*)d_in[13];
  float* out = (float*)d_out;

  float* ws = (float*)d_ws;
  const size_t ME  = (size_t)M_ * E_;          // 8,404,992
  const size_t BLL = (size_t)B_ * L_ * L_;     // 8,421,408
  float* src = ws;                 // M x E
  float* qb  = ws + ME;            // M x E   (also attn_out / fc2 out)
  float* kb  = ws + 2 * ME;        // M x E
  float* w2  = ws + 3 * ME;        // B x L x L   (overlaid with hid)
  float* hid = ws + 3 * ME;        // M x F       (w2 dead when hid live)
  (void)BLL; (void)ws_size; (void)in_sizes; (void)n_in; (void)out_size;

  k_embed<<<dim3((B_ * L_ * E_ + 255) / 256), 256, 0, stream>>>(x, tok_w, tok_b, src);

  for (int i = 0; i < NL_; ++i) {
    const float* wq = in_proj_w + (size_t)i * 3 * E_ * E_;
    const float* wk = wq + (size_t)E_ * E_;
    const float* bq = in_proj_b + (size_t)i * 3 * E_;
    const float* bk = bq + E_;

    dim3 gqk((M_ + 63) / 64, E_ / 64);
    k_gemm_nt<<<gqk, 256, 0, stream>>>(src, wq, bq, qb, M_, E_, E_, 0);
    k_gemm_nt<<<gqk, 256, 0, stream>>>(src, wk, bk, kb, M_, E_, E_, 0);

    k_attn<<<dim3(L_, B_), 256, 0, stream>>>(qb, kb, bias, w2);

    // attn_out (into qb): per-batch w2[b] (LxL) @ src[b] (LxE)
    k_gemm_nn_b<<<dim3((L_ + 63) / 64, E_ / 64, B_), 256, 0, stream>>>(
        w2, src, qb, L_, E_, L_);

    k_add_ln<<<M_, 256, 0, stream>>>(src, qb,
        ln1_w + (size_t)i * E_, ln1_b + (size_t)i * E_, src);

    k_gemm_nt<<<dim3((M_ + 63) / 64, F_ / 64), 256, 0, stream>>>(
        src, fc1_w + (size_t)i * F_ * E_, fc1_b + (size_t)i * F_, hid,
        M_, F_, E_, 1);
    k_gemm_nt<<<dim3((M_ + 63) / 64, E_ / 64), 256, 0, stream>>>(
        hid, fc2_w + (size_t)i * E_ * F_, fc2_b + (size_t)i * E_, qb,
        M_, E_, F_, 0);

    k_add_ln<<<M_, 256, 0, stream>>>(src, qb,
        ln2_w + (size_t)i * E_, ln2_b + (size_t)i * E_, src);
  }

  k_extract<<<dim3((B_ * E_ + 255) / 256), 256, 0, stream>>>(src, out);
}

// Round 2
// 10015.807 us; speedup vs baseline: 3.0436x; 3.0436x over previous
//
#include <hip/hip_runtime.h>
#include <hip/hip_bf16.h>
#include <math.h>

#define E_ 512
#define H_ 8
#define NL_ 6
#define F_ 1024
#define S_ 512
#define L_ 513
#define LP_ 528      // L padded to multiple of 16
#define B_ 32
#define DH_ 64
#define M_ (B_*L_)   // 16416
#define EPS_ 1e-5f
#define NMT_ (LP_/16)  // 33 m-tiles

typedef __attribute__((ext_vector_type(8))) short short8;
typedef __attribute__((ext_vector_type(4))) float f32x4;

// ---------------- block reduce helper (blockDim.x == 256, 4 waves) --------
__device__ __forceinline__ float blk_sum(float v, float* red) {
  #pragma unroll
  for (int off = 32; off > 0; off >>= 1) v += __shfl_down(v, off);
  int wid = threadIdx.x >> 6;
  if ((threadIdx.x & 63) == 0) red[wid] = v;
  __syncthreads();
  if (threadIdx.x == 0) {
    red[0] = (red[0] + red[1]) + (red[2] + red[3]);
  }
  __syncthreads();
  float r = red[0];
  __syncthreads();
  return r;
}

__device__ __forceinline__ unsigned short f2bf(float f) {
  union { float f; unsigned u; } v; v.f = f;
  unsigned r = v.u + 0x7FFF + ((v.u >> 16) & 1);   // round-nearest-even
  return (unsigned short)(r >> 16);
}

// ---------------- embed: src = tok_w * x_num + tok_b ----------------------
__global__ __launch_bounds__(256) void k_embed(
    const float* __restrict__ x, const float* __restrict__ tok_w,
    const float* __restrict__ tok_b, float* __restrict__ src) {
  int idx = blockIdx.x * 256 + threadIdx.x;
  if (idx >= B_ * L_ * E_) return;
  int e  = idx & (E_ - 1);
  int bl = idx >> 9;          // E_ = 512
  int l  = bl % L_;
  int b  = bl / L_;
  float xv = (l == 0) ? 1.0f : x[b * S_ + (l - 1)];
  src[idx] = tok_w[l * E_ + e] * xv + tok_b[l * E_ + e];
}

// ---------------- C = A @ W^T + bias (optionally relu) --------------------
__global__ __launch_bounds__(256) void k_gemm_nt(
    const float* __restrict__ A, const float* __restrict__ W,
    const float* __restrict__ bias, float* __restrict__ C,
    int M, int N, int K, int relu) {
  __shared__ float As[16][64];
  __shared__ float Ws[16][64];
  int m0 = blockIdx.x * 64, n0 = blockIdx.y * 64;
  int t = threadIdx.x;
  int tx = t & 15, ty = t >> 4;
  float acc[4][4] = {};
  for (int kt = 0; kt < K; kt += 16) {
    #pragma unroll
    for (int i = 0; i < 4; ++i) {
      int lin = t + i * 256;
      int kk = lin & 15, mm = lin >> 4;
      int gm = m0 + mm;
      As[kk][mm] = (gm < M) ? A[(size_t)gm * K + kt + kk] : 0.0f;
      Ws[kk][mm] = W[(size_t)(n0 + mm) * K + kt + kk];
    }
    __syncthreads();
    #pragma unroll
    for (int kk = 0; kk < 16; ++kk) {
      float a[4], w[4];
      #pragma unroll
      for (int i = 0; i < 4; ++i) a[i] = As[kk][ty * 4 + i];
      #pragma unroll
      for (int j = 0; j < 4; ++j) w[j] = Ws[kk][tx * 4 + j];
      #pragma unroll
      for (int i = 0; i < 4; ++i)
        #pragma unroll
        for (int j = 0; j < 4; ++j) acc[i][j] += a[i] * w[j];
    }
    __syncthreads();
  }
  #pragma unroll
  for (int i = 0; i < 4; ++i) {
    int gm = m0 + ty * 4 + i;
    if (gm >= M) continue;
    #pragma unroll
    for (int j = 0; j < 4; ++j) {
      int gn = n0 + tx * 4 + j;
      float v = acc[i][j] + bias[gn];
      if (relu) v = fmaxf(v, 0.0f);
      C[(size_t)gm * N + gn] = v;
    }
  }
}

// ---------------- batched C[b] = A[b] @ B[b] ------------------------------
__global__ __launch_bounds__(256) void k_gemm_nn_b(
    const float* __restrict__ Ag, const float* __restrict__ Bg,
    float* __restrict__ Cg, int M, int N, int K) {
  const float* A  = Ag + (size_t)blockIdx.z * M * K;
  const float* Bp = Bg + (size_t)blockIdx.z * K * N;
  float*       C  = Cg + (size_t)blockIdx.z * M * N;
  __shared__ float As[16][64];
  __shared__ float Bs[16][64];
  int m0 = blockIdx.x * 64, n0 = blockIdx.y * 64;
  int t = threadIdx.x;
  int tx = t & 15, ty = t >> 4;
  float acc[4][4] = {};
  for (int kt = 0; kt < K; kt += 16) {
    #pragma unroll
    for (int i = 0; i < 4; ++i) {
      int lin = t + i * 256;
      int kk = lin & 15, mm = lin >> 4;
      int gm = m0 + mm;
      As[kk][mm] = (gm < M && kt + kk < K) ? A[(size_t)gm * K + kt + kk] : 0.0f;
      int kk2 = lin >> 6, nn = lin & 63;
      Bs[kk2][nn] = (kt + kk2 < K) ? Bp[(size_t)(kt + kk2) * N + n0 + nn] : 0.0f;
    }
    __syncthreads();
    #pragma unroll
    for (int kk = 0; kk < 16; ++kk) {
      float a[4], w[4];
      #pragma unroll
      for (int i = 0; i < 4; ++i) a[i] = As[kk][ty * 4 + i];
      #pragma unroll
      for (int j = 0; j < 4; ++j) w[j] = Bs[kk][tx * 4 + j];
      #pragma unroll
      for (int i = 0; i < 4; ++i)
        #pragma unroll
        for (int j = 0; j < 4; ++j) acc[i][j] += a[i] * w[j];
    }
    __syncthreads();
  }
  #pragma unroll
  for (int i = 0; i < 4; ++i) {
    int gm = m0 + ty * 4 + i;
    if (gm >= M) continue;
    #pragma unroll
    for (int j = 0; j < 4; ++j) {
      int gn = n0 + tx * 4 + j;
      C[(size_t)gm * N + gn] = acc[i][j];
    }
  }
}

// ---------------- convert q,k fp32 (B,L,E) -> bf16 padded (B,LP,E) --------
__global__ __launch_bounds__(256) void k_cvt_qk(
    const float* __restrict__ qf, const float* __restrict__ kf,
    unsigned short* __restrict__ qh, unsigned short* __restrict__ kh) {
  int idx = blockIdx.x * 256 + threadIdx.x;       // quads of elements
  if (idx >= B_ * LP_ * E_ / 4) return;
  int e4  = idx & (E_ / 4 - 1);
  int row = idx >> 7;                             // b*LP_ + lp
  int lp  = row % LP_;
  int b   = row / LP_;
  float4 qv = {0.f, 0.f, 0.f, 0.f}, kv = {0.f, 0.f, 0.f, 0.f};
  if (lp < L_) {
    size_t off = ((size_t)(b * L_ + lp)) * E_ + e4 * 4;
    qv = *reinterpret_cast<const float4*>(qf + off);
    kv = *reinterpret_cast<const float4*>(kf + off);
  }
  ushort4 qo, ko;
  qo.x = f2bf(qv.x); qo.y = f2bf(qv.y); qo.z = f2bf(qv.z); qo.w = f2bf(qv.w);
  ko.x = f2bf(kv.x); ko.y = f2bf(kv.y); ko.z = f2bf(kv.z); ko.w = f2bf(kv.w);
  size_t oo = (size_t)row * E_ + e4 * 4;
  *reinterpret_cast<ushort4*>(qh + oo) = qo;
  *reinterpret_cast<ushort4*>(kh + oo) = ko;
}

// ---------------- fused attention probabilities (MFMA) --------------------
// One block per (l-tile of 16, b). Per head: 16x513 score panel via MFMA,
// row softmax, accumulate head-average; then bias + second softmax -> W2.
__global__ __launch_bounds__(256) void k_attn_mfma(
    const unsigned short* __restrict__ Qh, const unsigned short* __restrict__ Kh,
    const float* __restrict__ bias, float* __restrict__ W2) {
  __shared__ float s[16][LP_];      // 33792 B
  __shared__ float avg[16][LP_];    // 33792 B
  const int lt = blockIdx.x, b = blockIdx.y;
  const int t = threadIdx.x;
  const int wave = t >> 6, lane = t & 63;
  const int fr = lane & 15;         // fragment row (A) / col (B)
  const int k8 = (lane >> 4) * 8;   // fragment k offset (8 contiguous)
  const int row = t >> 4;           // softmax row 0..15 (16 threads/row, same wave)
  const int sub = t & 15;

  for (int i = t; i < 16 * LP_; i += 256) (&avg[0][0])[i] = 0.f;

  // preload Q fragments: 8 heads x 2 k-chunks of 32
  const unsigned short* qrow = Qh + ((size_t)b * LP_ + lt * 16 + fr) * E_;
  short8 qfrag[16];
  #pragma unroll
  for (int h = 0; h < H_; ++h)
    #pragma unroll
    for (int c = 0; c < 2; ++c)
      qfrag[h * 2 + c] =
          *reinterpret_cast<const short8*>(qrow + h * DH_ + c * 32 + k8);

  const unsigned short* kbase = Kh + (size_t)b * LP_ * E_;
  __syncthreads();

  const float scale = 0.125f;       // 1/sqrt(DH)
  for (int h = 0; h < H_; ++h) {
    for (int mt = wave; mt < NMT_; mt += 4) {
      f32x4 acc = {0.f, 0.f, 0.f, 0.f};
      #pragma unroll
      for (int c = 0; c < 2; ++c) {
        short8 kfr = *reinterpret_cast<const short8*>(
            kbase + (size_t)(mt * 16 + fr) * E_ + h * DH_ + c * 32 + k8);
        acc = __builtin_amdgcn_mfma_f32_16x16x32_bf16(qfrag[h * 2 + c], kfr,
                                                      acc, 0, 0, 0);
      }
      int m = mt * 16 + fr;         // C/D: col = lane&15
      #pragma unroll
      for (int i = 0; i < 4; ++i) {
        int r = (lane >> 4) * 4 + i;  // C/D: row = (lane>>4)*4 + reg
        s[r][m] = (m < L_) ? acc[i] * scale : -INFINITY;
      }
    }
    __syncthreads();
    // per-row softmax over m, accumulate into avg
    float mx = -INFINITY;
    #pragma unroll
    for (int j = 0; j < NMT_; ++j) mx = fmaxf(mx, s[row][sub + 16 * j]);
    #pragma unroll
    for (int off = 8; off >= 1; off >>= 1) mx = fmaxf(mx, __shfl_xor(mx, off));
    float e[NMT_];
    float sm = 0.f;
    #pragma unroll
    for (int j = 0; j < NMT_; ++j) {
      e[j] = __expf(s[row][sub + 16 * j] - mx);
      sm += e[j];
    }
    #pragma unroll
    for (int off = 8; off >= 1; off >>= 1) sm += __shfl_xor(sm, off);
    float inv = 1.f / sm;
    #pragma unroll
    for (int j = 0; j < NMT_; ++j) avg[row][sub + 16 * j] += e[j] * inv;
    __syncthreads();
  }

  // second softmax: v = avg/H + bias[l,:]
  int l = lt * 16 + row;
  if (l < L_) {
    float v[NMT_];
    float mx = -INFINITY;
    #pragma unroll
    for (int j = 0; j < NMT_; ++j) {
      int m = sub + 16 * j;
      v[j] = (m < L_) ? avg[row][m] * (1.f / H_) + bias[(size_t)l * L_ + m]
                      : -INFINITY;
      mx = fmaxf(mx, v[j]);
    }
    #pragma unroll
    for (int off = 8; off >= 1; off >>= 1) mx = fmaxf(mx, __shfl_xor(mx, off));
    float e[NMT_];
    float sm = 0.f;
    #pragma unroll
    for (int j = 0; j < NMT_; ++j) {
      e[j] = __expf(v[j] - mx);
      sm += e[j];
    }
    #pragma unroll
    for (int off = 8; off >= 1; off >>= 1) sm += __shfl_xor(sm, off);
    float inv = 1.f / sm;
    float* w2row = W2 + ((size_t)b * L_ + l) * L_;
    #pragma unroll
    for (int j = 0; j < NMT_; ++j) {
      int m = sub + 16 * j;
      if (m < L_) w2row[m] = e[j] * inv;
    }
  }
}

// ---------------- out = LayerNorm(x + y) * w + b --------------------------
__global__ __launch_bounds__(256) void k_add_ln(
    const float* __restrict__ X, const float* __restrict__ Y,
    const float* __restrict__ w, const float* __restrict__ bb,
    float* __restrict__ out) {
  int row = blockIdx.x;
  int t = threadIdx.x;
  const float* xr = X + (size_t)row * E_;
  const float* yr = Y + (size_t)row * E_;
  __shared__ float red[4];
  float v0 = xr[t] + yr[t];
  float v1 = xr[t + 256] + yr[t + 256];
  float mean = blk_sum(v0 + v1, red) * (1.0f / E_);
  float d0 = v0 - mean, d1 = v1 - mean;
  float var = blk_sum(d0 * d0 + d1 * d1, red) * (1.0f / E_);
  float inv = rsqrtf(var + EPS_);
  float* orow = out + (size_t)row * E_;
  orow[t]       = d0 * inv * w[t]       + bb[t];
  orow[t + 256] = d1 * inv * w[t + 256] + bb[t + 256];
}

// ---------------- extract out = src[:, 0, :] ------------------------------
__global__ __launch_bounds__(256) void k_extract(
    const float* __restrict__ src, float* __restrict__ out) {
  int i = blockIdx.x * 256 + threadIdx.x;
  if (i >= B_ * E_) return;
  int b = i >> 9, e = i & (E_ - 1);
  out[i] = src[((size_t)b * L_) * E_ + e];
}

extern "C" void kernel_launch(void* const* d_in, const int* in_sizes, int n_in,
                              void* d_out, int out_size, void* d_ws, size_t ws_size,
                              hipStream_t stream) {
  const float* x        = (const float*)d_in[0];
  const float* tok_w    = (const float*)d_in[1];
  const float* tok_b    = (const float*)d_in[2];
  const float* bias     = (const float*)d_in[3];
  const float* in_proj_w= (const float*)d_in[4];
  const float* in_proj_b= (const float*)d_in[5];
  const float* fc1_w    = (const float*)d_in[6];
  const float* fc1_b    = (const float*)d_in[7];
  const float* fc2_w    = (const float*)d_in[8];
  const float* fc2_b    = (const float*)d_in[9];
  const float* ln1_w    = (const float*)d_in[10];
  const float* ln1_b    = (const float*)d_in[11];
  const float* ln2_w    = (const float*)d_in[12];
  const float* ln2_b    = (const float*)d_in[13];
  float* out = (float*)d_out;

  float* ws = (float*)d_ws;
  const size_t ME  = (size_t)M_ * E_;          // 8,404,992
  const size_t BLL = (size_t)B_ * L_ * L_;     // 8,421,408
  const size_t PQK = (size_t)B_ * LP_ * E_;    // 8,650,752 bf16 elems each
  float* src = ws;                   // M x E
  float* qb  = ws + ME;              // M x E (q fp32; later attn_out/fc2_out)
  float* kb  = ws + 2 * ME;          // M x E (k fp32)
  float* w2  = ws + 3 * ME;          // B x L x L
  float* hid = ws + 3 * ME;          // M x F  (overlays w2+qbh+kbh; disjoint in time)
  unsigned short* qbh = (unsigned short*)(ws + 3 * ME + BLL);
  unsigned short* kbh = qbh + PQK;
  (void)ws_size; (void)in_sizes; (void)n_in; (void)out_size;

  k_embed<<<dim3((B_ * L_ * E_ + 255) / 256), 256, 0, stream>>>(x, tok_w, tok_b, src);

  for (int i = 0; i < NL_; ++i) {
    const float* wq = in_proj_w + (size_t)i * 3 * E_ * E_;
    const float* wk = wq + (size_t)E_ * E_;
    const float* bq = in_proj_b + (size_t)i * 3 * E_;
    const float* bk = bq + E_;

    dim3 gqk((M_ + 63) / 64, E_ / 64);
    k_gemm_nt<<<gqk, 256, 0, stream>>>(src, wq, bq, qb, M_, E_, E_, 0);
    k_gemm_nt<<<gqk, 256, 0, stream>>>(src, wk, bk, kb, M_, E_, E_, 0);

    k_cvt_qk<<<dim3((B_ * LP_ * E_ / 4 + 255) / 256), 256, 0, stream>>>(
        qb, kb, qbh, kbh);

    k_attn_mfma<<<dim3(NMT_, B_), 256, 0, stream>>>(qbh, kbh, bias, w2);

    // attn_out (into qb): per-batch w2[b] (LxL) @ src[b] (LxE)
    k_gemm_nn_b<<<dim3((L_ + 63) / 64, E_ / 64, B_), 256, 0, stream>>>(
        w2, src, qb, L_, E_, L_);

    k_add_ln<<<M_, 256, 0, stream>>>(src, qb,
        ln1_w + (size_t)i * E_, ln1_b + (size_t)i * E_, src);

    k_gemm_nt<<<dim3((M_ + 63) / 64, F_ / 64), 256, 0, stream>>>(
        src, fc1_w + (size_t)i * F_ * E_, fc1_b + (size_t)i * F_, hid,
        M_, F_, E_, 1);
    k_gemm_nt<<<dim3((M_ + 63) / 64, E_ / 64), 256, 0, stream>>>(
        hid, fc2_w + (size_t)i * E_ * F_, fc2_b + (size_t)i * E_, qb,
        M_, E_, F_, 0);

    k_add_ln<<<M_, 256, 0, stream>>>(src, qb,
        ln2_w + (size_t)i * E_, ln2_b + (size_t)i * E_, src);
  }

  k_extract<<<dim3((B_ * E_ + 255) / 256), 256, 0, stream>>>(src, out);
}

// Round 3
// 2731.159 us; speedup vs baseline: 11.1614x; 3.6672x over previous
//
#include <hip/hip_runtime.h>
#include <hip/hip_bf16.h>
#include <math.h>

#define E_ 512
#define H_ 8
#define NL_ 6
#define F_ 1024
#define S_ 512
#define L_ 513
#define B_ 32
#define DH_ 64
#define M_ (B_*L_)      // 16416
#define EPS_ 1e-5f
#define NMT_ 33         // attn m-tiles (528/16)
#define KP_ 576         // padded K for attn_out gemm (multiple of 64)
#define W2R_ 640        // w2 rows alloc per batch (5 tiles of 128)
#define QKS_ 1024       // qkh row stride in ushorts (q||k)

typedef __attribute__((ext_vector_type(8))) short short8;
typedef __attribute__((ext_vector_type(4))) float f32x4;
typedef unsigned short u16;
typedef unsigned int u32;

__device__ __forceinline__ u16 f2bf(float f) {
  union { float f; unsigned u; } v; v.f = f;
  unsigned r = v.u + 0x7FFF + ((v.u >> 16) & 1);   // RNE
  return (u16)(r >> 16);
}

__device__ __forceinline__ void gl16(const void* g, void* l) {
  __builtin_amdgcn_global_load_lds(
      (const __attribute__((address_space(1))) u32*)g,
      (__attribute__((address_space(3))) u32*)l, 16, 0, 0);
}

// ---------------- block reduce (blockDim=256) -----------------------------
__device__ __forceinline__ float blk_sum(float v, float* red) {
  #pragma unroll
  for (int off = 32; off > 0; off >>= 1) v += __shfl_down(v, off);
  int wid = threadIdx.x >> 6;
  if ((threadIdx.x & 63) == 0) red[wid] = v;
  __syncthreads();
  if (threadIdx.x == 0) red[0] = (red[0] + red[1]) + (red[2] + red[3]);
  __syncthreads();
  float r = red[0];
  __syncthreads();
  return r;
}

// ---------------- weight fp32 -> bf16 (all layers) ------------------------
__global__ __launch_bounds__(256) void k_cvt(
    const float* __restrict__ srcp, u16* __restrict__ dst,
    long epl, long src_stride) {        // epl multiple of 4
  long idx = ((long)blockIdx.x * 256 + threadIdx.x) * 4;
  long layer = idx / epl;
  if (layer >= NL_) return;
  long j = idx - layer * epl;
  float4 v = *reinterpret_cast<const float4*>(srcp + layer * src_stride + j);
  ushort4 o;
  o.x = f2bf(v.x); o.y = f2bf(v.y); o.z = f2bf(v.z); o.w = f2bf(v.w);
  *reinterpret_cast<ushort4*>(dst + idx) = o;
}

// ---------------- embed: src = tok_w * x_num + tok_b (fp32 + bf16) --------
__global__ __launch_bounds__(256) void k_embed(
    const float* __restrict__ x, const float* __restrict__ tok_w,
    const float* __restrict__ tok_b, float* __restrict__ src,
    u16* __restrict__ srch) {
  int idx = blockIdx.x * 256 + threadIdx.x;
  if (idx >= B_ * L_ * E_) return;
  int e  = idx & (E_ - 1);
  int bl = idx >> 9;
  int l  = bl % L_;
  int b  = bl / L_;
  float xv = (l == 0) ? 1.0f : x[b * S_ + (l - 1)];
  float v = tok_w[l * E_ + e] * xv + tok_b[l * E_ + e];
  src[idx] = v;
  srch[idx] = f2bf(v);
}

// ---------------- unified bf16 MFMA GEMM: C = A @ W^T + bias --------------
// A: MxK bf16 row-major; W: NxK bf16 row-major (k-contig both).
// MODE 0: fp32 out; 1: bf16 out; 2: bf16 out + relu. Batched via blockIdx.z.
template<int MODE>
__global__ __launch_bounds__(256) void k_gemm(
    const u16* __restrict__ Ag, const u16* __restrict__ Wg,
    const float* __restrict__ bias, void* __restrict__ Cg,
    int N, int K, int Mbound, long astride, long wstride, long cstride) {
  __shared__ u16 As[128 * 64];
  __shared__ u16 Ws[128 * 64];
  const int z = blockIdx.z;
  const u16* A = Ag + (size_t)z * astride;
  const u16* W = Wg + (size_t)z * wstride;
  const int m0 = blockIdx.x * 128, n0 = blockIdx.y * 128;
  const int t = threadIdx.x, wave = t >> 6, lane = t & 63;
  const int fr = lane & 15, k8 = (lane >> 4) * 8;
  const int srow = lane >> 3, scol = (lane & 7) * 8;
  const int wm = wave >> 1, wn = wave & 1;
  f32x4 acc[4][4] = {};
  for (int kt = 0; kt < K; kt += 64) {
    #pragma unroll
    for (int i = 0; i < 4; ++i) {
      int slot = wave * 4 + i;
      gl16(A + (size_t)(m0 + slot * 8 + srow) * K + kt + scol, As + slot * 512);
      gl16(W + (size_t)(n0 + slot * 8 + srow) * K + kt + scol, Ws + slot * 512);
    }
    __syncthreads();
    short8 a[4][2], b[4][2];
    #pragma unroll
    for (int mi = 0; mi < 4; ++mi)
      #pragma unroll
      for (int c = 0; c < 2; ++c)
        a[mi][c] = *reinterpret_cast<const short8*>(
            As + (wm * 64 + mi * 16 + fr) * 64 + c * 32 + k8);
    #pragma unroll
    for (int ni = 0; ni < 4; ++ni)
      #pragma unroll
      for (int c = 0; c < 2; ++c)
        b[ni][c] = *reinterpret_cast<const short8*>(
            Ws + (wn * 64 + ni * 16 + fr) * 64 + c * 32 + k8);
    #pragma unroll
    for (int c = 0; c < 2; ++c)
      #pragma unroll
      for (int mi = 0; mi < 4; ++mi)
        #pragma unroll
        for (int ni = 0; ni < 4; ++ni)
          acc[mi][ni] = __builtin_amdgcn_mfma_f32_16x16x32_bf16(
              a[mi][c], b[ni][c], acc[mi][ni], 0, 0, 0);
    __syncthreads();
  }
  const int r0 = (lane >> 4) * 4;
  #pragma unroll
  for (int mi = 0; mi < 4; ++mi) {
    #pragma unroll
    for (int ni = 0; ni < 4; ++ni) {
      int col = n0 + wn * 64 + ni * 16 + fr;
      float bs = bias ? bias[col] : 0.f;
      #pragma unroll
      for (int i = 0; i < 4; ++i) {
        int row = m0 + wm * 64 + mi * 16 + r0 + i;
        if (row < Mbound) {
          float v = acc[mi][ni][i] + bs;
          if (MODE == 2) v = fmaxf(v, 0.f);
          size_t o = (size_t)z * cstride + (size_t)row * N + col;
          if (MODE == 0) ((float*)Cg)[o] = v;
          else           ((u16*)Cg)[o] = f2bf(v);
        }
      }
    }
  }
}

// ---------------- fused attention probabilities (MFMA) --------------------
// qkh rows: [q(512) || k(512)] bf16, row stride QKS_. Writes w2 bf16,
// per batch W2R_ x KP_ with zero pad cols.
__global__ __launch_bounds__(256) void k_attn_mfma(
    const u16* __restrict__ QK, const float* __restrict__ bias,
    u16* __restrict__ W2) {
  __shared__ float s[16][528];
  __shared__ float avg[16][528];
  const int lt = blockIdx.x, b = blockIdx.y;
  const int t = threadIdx.x;
  const int wave = t >> 6, lane = t & 63;
  const int fr = lane & 15, k8 = (lane >> 4) * 8;
  const int row = t >> 4, sub = t & 15;

  for (int i = t; i < 16 * 528; i += 256) (&avg[0][0])[i] = 0.f;

  const u16* qrow = QK + ((size_t)b * L_ + lt * 16 + fr) * QKS_;
  short8 qfrag[16];
  #pragma unroll
  for (int h = 0; h < H_; ++h)
    #pragma unroll
    for (int c = 0; c < 2; ++c)
      qfrag[h * 2 + c] =
          *reinterpret_cast<const short8*>(qrow + h * DH_ + c * 32 + k8);

  const u16* kbase = QK + (size_t)b * L_ * QKS_ + 512;
  __syncthreads();

  const float scale = 0.125f;
  for (int h = 0; h < H_; ++h) {
    for (int mt = wave; mt < NMT_; mt += 4) {
      f32x4 acc = {0.f, 0.f, 0.f, 0.f};
      #pragma unroll
      for (int c = 0; c < 2; ++c) {
        short8 kfr = *reinterpret_cast<const short8*>(
            kbase + (size_t)(mt * 16 + fr) * QKS_ + h * DH_ + c * 32 + k8);
        acc = __builtin_amdgcn_mfma_f32_16x16x32_bf16(qfrag[h * 2 + c], kfr,
                                                      acc, 0, 0, 0);
      }
      int m = mt * 16 + fr;
      #pragma unroll
      for (int i = 0; i < 4; ++i) {
        int r = (lane >> 4) * 4 + i;
        s[r][m] = (m < L_) ? acc[i] * scale : -INFINITY;
      }
    }
    __syncthreads();
    float mx = -INFINITY;
    #pragma unroll
    for (int j = 0; j < NMT_; ++j) mx = fmaxf(mx, s[row][sub + 16 * j]);
    #pragma unroll
    for (int off = 8; off >= 1; off >>= 1) mx = fmaxf(mx, __shfl_xor(mx, off));
    float e[NMT_];
    float sm = 0.f;
    #pragma unroll
    for (int j = 0; j < NMT_; ++j) {
      e[j] = __expf(s[row][sub + 16 * j] - mx);
      sm += e[j];
    }
    #pragma unroll
    for (int off = 8; off >= 1; off >>= 1) sm += __shfl_xor(sm, off);
    float inv = 1.f / sm;
    #pragma unroll
    for (int j = 0; j < NMT_; ++j) avg[row][sub + 16 * j] += e[j] * inv;
    __syncthreads();
  }

  int l = lt * 16 + row;
  if (l < L_) {
    float v[NMT_];
    float mx = -INFINITY;
    #pragma unroll
    for (int j = 0; j < NMT_; ++j) {
      int m = sub + 16 * j;
      v[j] = (m < L_) ? avg[row][m] * (1.f / H_) + bias[(size_t)l * L_ + m]
                      : -INFINITY;
      mx = fmaxf(mx, v[j]);
    }
    #pragma unroll
    for (int off = 8; off >= 1; off >>= 1) mx = fmaxf(mx, __shfl_xor(mx, off));
    float e[NMT_];
    float sm = 0.f;
    #pragma unroll
    for (int j = 0; j < NMT_; ++j) {
      e[j] = __expf(v[j] - mx);
      sm += e[j];
    }
    #pragma unroll
    for (int off = 8; off >= 1; off >>= 1) sm += __shfl_xor(sm, off);
    float inv = 1.f / sm;
    u16* w2row = W2 + ((size_t)b * W2R_ + l) * KP_;
    #pragma unroll
    for (int j = 0; j < KP_ / 16; ++j) {   // 36
      int m = sub + 16 * j;
      float val = 0.f;
      if (j < NMT_ && m < L_) val = e[j] * inv;
      w2row[m] = f2bf(val);
    }
  }
}

// ---------------- transpose src_bf16 (B,L,E) -> srcT (B,E,KP_) ------------
__global__ __launch_bounds__(256) void k_transpose(
    const u16* __restrict__ src, u16* __restrict__ dst) {
  __shared__ u16 T[32][34];
  const int b = blockIdx.z, e0 = blockIdx.x * 32, m0 = blockIdx.y * 32;
  const int t = threadIdx.x;
  const int c = t & 31, r = t >> 5;   // 8 rows/pass
  #pragma unroll
  for (int j = 0; j < 4; ++j) {
    int m = m0 + r + j * 8;
    T[r + j * 8][c] =
        (m < L_) ? src[((size_t)b * L_ + m) * E_ + e0 + c] : (u16)0;
  }
  __syncthreads();
  #pragma unroll
  for (int j = 0; j < 4; ++j) {
    int e = e0 + r + j * 8;
    dst[((size_t)b * E_ + e) * KP_ + m0 + c] = T[c][r + j * 8];
  }
}

// ---------------- out = LayerNorm(x + y) * w + b (fp32 + bf16) ------------
__global__ __launch_bounds__(256) void k_add_ln(
    const float* __restrict__ X, const float* __restrict__ Y,
    const float* __restrict__ w, const float* __restrict__ bb,
    float* __restrict__ out, u16* __restrict__ outh) {
  int row = blockIdx.x;
  int t = threadIdx.x;
  const float* xr = X + (size_t)row * E_;
  const float* yr = Y + (size_t)row * E_;
  __shared__ float red[4];
  float v0 = xr[t] + yr[t];
  float v1 = xr[t + 256] + yr[t + 256];
  float mean = blk_sum(v0 + v1, red) * (1.0f / E_);
  float d0 = v0 - mean, d1 = v1 - mean;
  float var = blk_sum(d0 * d0 + d1 * d1, red) * (1.0f / E_);
  float inv = rsqrtf(var + EPS_);
  float o0 = d0 * inv * w[t] + bb[t];
  float o1 = d1 * inv * w[t + 256] + bb[t + 256];
  float* orow = out + (size_t)row * E_;
  orow[t] = o0; orow[t + 256] = o1;
  u16* oh = outh + (size_t)row * E_;
  oh[t] = f2bf(o0); oh[t + 256] = f2bf(o1);
}

// ---------------- extract out = src[:, 0, :] ------------------------------
__global__ __launch_bounds__(256) void k_extract(
    const float* __restrict__ src, float* __restrict__ out) {
  int i = blockIdx.x * 256 + threadIdx.x;
  if (i >= B_ * E_) return;
  int b = i >> 9, e = i & (E_ - 1);
  out[i] = src[((size_t)b * L_) * E_ + e];
}

extern "C" void kernel_launch(void* const* d_in, const int* in_sizes, int n_in,
                              void* d_out, int out_size, void* d_ws, size_t ws_size,
                              hipStream_t stream) {
  const float* x        = (const float*)d_in[0];
  const float* tok_w    = (const float*)d_in[1];
  const float* tok_b    = (const float*)d_in[2];
  const float* bias     = (const float*)d_in[3];
  const float* in_proj_w= (const float*)d_in[4];
  const float* in_proj_b= (const float*)d_in[5];
  const float* fc1_w    = (const float*)d_in[6];
  const float* fc1_b    = (const float*)d_in[7];
  const float* fc2_w    = (const float*)d_in[8];
  const float* fc2_b    = (const float*)d_in[9];
  const float* ln1_w    = (const float*)d_in[10];
  const float* ln1_b    = (const float*)d_in[11];
  const float* ln2_w    = (const float*)d_in[12];
  const float* ln2_b    = (const float*)d_in[13];
  float* out = (float*)d_out;
  (void)in_sizes; (void)n_in; (void)out_size; (void)ws_size;

  float* ws = (float*)d_ws;
  const size_t ME  = (size_t)M_ * E_;        // 8,404,992 floats
  const size_t SLK = 65536;                  // 256KB slack (floats)
  float* src  = ws;                          // ME
  float* tmp  = src + ME;                    // ME
  u16*   srch = (u16*)(tmp + ME);            // M x E bf16 (+slack)
  u16*   qkh  = (u16*)((float*)srch + ME / 2 + SLK);   // M x 1024 bf16 (+slack)
  u16*   hid  = qkh;                                    // overlay (M x F bf16)
  u16*   w2   = (u16*)((float*)qkh + ME + SLK);         // B x W2R_ x KP_ bf16
  const size_t w2f = (size_t)B_ * W2R_ * KP_ / 2;
  u16*   srcT = (u16*)((float*)w2 + w2f);               // B x E x KP_ bf16
  const size_t sTf = (size_t)B_ * E_ * KP_ / 2;
  u16*   wqk  = (u16*)((float*)srcT + sTf);             // NL x 1024 x 512
  u16*   w1h  = wqk + (size_t)NL_ * F_ * E_;            // NL x 1024 x 512
  u16*   w2h  = w1h + (size_t)NL_ * F_ * E_;            // NL x 512 x 1024

  // weights -> bf16 (epl = 2^19)
  k_cvt<<<3072, 256, 0, stream>>>(in_proj_w, wqk, 524288L, 786432L);
  k_cvt<<<3072, 256, 0, stream>>>(fc1_w, w1h, 524288L, 524288L);
  k_cvt<<<3072, 256, 0, stream>>>(fc2_w, w2h, 524288L, 524288L);

  k_embed<<<dim3((B_ * L_ * E_ + 255) / 256), 256, 0, stream>>>(
      x, tok_w, tok_b, src, srch);

  const int MT = (M_ + 127) / 128;   // 129
  for (int i = 0; i < NL_; ++i) {
    // QK projection: [q||k] = src @ [wq;wk]^T + [bq;bk]  -> qkh bf16
    k_gemm<1><<<dim3(MT, 8, 1), 256, 0, stream>>>(
        srch, wqk + (size_t)i * F_ * E_, in_proj_b + (size_t)i * 3 * E_,
        qkh, 1024, 512, M_, 0, 0, 0);

    k_attn_mfma<<<dim3(NMT_, B_), 256, 0, stream>>>(qkh, bias, w2);

    k_transpose<<<dim3(16, KP_ / 32, B_), 256, 0, stream>>>(srch, srcT);

    // attn_out = w2 @ src  (batched NT vs srcT), fp32 -> tmp
    k_gemm<0><<<dim3(5, 4, 32), 256, 0, stream>>>(
        w2, srcT, (const float*)nullptr, tmp, E_, KP_, L_,
        (long)W2R_ * KP_, (long)E_ * KP_, (long)L_ * E_);

    k_add_ln<<<M_, 256, 0, stream>>>(src, tmp,
        ln1_w + (size_t)i * E_, ln1_b + (size_t)i * E_, src, srch);

    k_gemm<2><<<dim3(MT, 8, 1), 256, 0, stream>>>(
        srch, w1h + (size_t)i * F_ * E_, fc1_b + (size_t)i * F_,
        hid, 1024, 512, M_, 0, 0, 0);

    k_gemm<0><<<dim3(MT, 4, 1), 256, 0, stream>>>(
        hid, w2h + (size_t)i * E_ * F_, fc2_b + (size_t)i * E_,
        tmp, 512, 1024, M_, 0, 0, 0);

    k_add_ln<<<M_, 256, 0, stream>>>(src, tmp,
        ln2_w + (size_t)i * E_, ln2_b + (size_t)i * E_, src, srch);
  }

  k_extract<<<dim3((B_ * E_ + 255) / 256), 256, 0, stream>>>(src, out);
}

// Round 6
// 2473.293 us; speedup vs baseline: 12.3251x; 1.1043x over previous
//
#include <hip/hip_runtime.h>
#include <hip/hip_bf16.h>
#include <math.h>

#define E_ 512
#define H_ 8
#define NL_ 6
#define F_ 1024
#define S_ 512
#define L_ 513
#define B_ 32
#define DH_ 64
#define M_ (B_*L_)      // 16416
#define EPS_ 1e-5f
#define NMT_ 33         // attn m-tiles (528/16)
#define KP_ 576         // padded K for attn_out gemm (multiple of 64)
#define W2R_ 640        // w2 rows alloc per batch (5 tiles of 128)
#define QKS_ 1024       // qkh row stride in ushorts (q||k)

typedef __attribute__((ext_vector_type(8))) short short8;
typedef __attribute__((ext_vector_type(4))) float f32x4;
typedef unsigned short u16;
typedef unsigned int u32;

__device__ __forceinline__ u16 f2bf(float f) {
  union { float f; unsigned u; } v; v.f = f;
  unsigned r = v.u + 0x7FFF + ((v.u >> 16) & 1);   // RNE
  return (u16)(r >> 16);
}

__device__ __forceinline__ void gl16(const void* g, void* l) {
  __builtin_amdgcn_global_load_lds(
      (const __attribute__((address_space(1))) u32*)g,
      (__attribute__((address_space(3))) u32*)l, 16, 0, 0);
}

// ---------------- block reduce (blockDim=256) -----------------------------
__device__ __forceinline__ float blk_sum(float v, float* red) {
  #pragma unroll
  for (int off = 32; off > 0; off >>= 1) v += __shfl_down(v, off);
  int wid = threadIdx.x >> 6;
  if ((threadIdx.x & 63) == 0) red[wid] = v;
  __syncthreads();
  if (threadIdx.x == 0) red[0] = (red[0] + red[1]) + (red[2] + red[3]);
  __syncthreads();
  float r = red[0];
  __syncthreads();
  return r;
}

// ---------------- weight fp32 -> bf16 (all layers) ------------------------
__global__ __launch_bounds__(256) void k_cvt(
    const float* __restrict__ srcp, u16* __restrict__ dst,
    long epl, long src_stride) {        // epl multiple of 4
  long idx = ((long)blockIdx.x * 256 + threadIdx.x) * 4;
  long layer = idx / epl;
  if (layer >= NL_) return;
  long j = idx - layer * epl;
  float4 v = *reinterpret_cast<const float4*>(srcp + layer * src_stride + j);
  ushort4 o;
  o.x = f2bf(v.x); o.y = f2bf(v.y); o.z = f2bf(v.z); o.w = f2bf(v.w);
  *reinterpret_cast<ushort4*>(dst + idx) = o;
}

// ---------------- embed: src = tok_w * x_num + tok_b (fp32 + bf16) --------
__global__ __launch_bounds__(256) void k_embed(
    const float* __restrict__ x, const float* __restrict__ tok_w,
    const float* __restrict__ tok_b, float* __restrict__ src,
    u16* __restrict__ srch) {
  int idx = blockIdx.x * 256 + threadIdx.x;
  if (idx >= B_ * L_ * E_) return;
  int e  = idx & (E_ - 1);
  int bl = idx >> 9;
  int l  = bl % L_;
  int b  = bl / L_;
  float xv = (l == 0) ? 1.0f : x[b * S_ + (l - 1)];
  float v = tok_w[l * E_ + e] * xv + tok_b[l * E_ + e];
  src[idx] = v;
  srch[idx] = f2bf(v);
}

// ---------------- unified bf16 MFMA GEMM: C = A @ W^T + bias --------------
// A: MxK bf16 row-major; W: NxK bf16 row-major (k-contig both).
// MODE 0: fp32 out; 1: bf16 out; 2: bf16 out + relu. Batched via blockIdx.z.
template<int MODE>
__global__ __launch_bounds__(256) void k_gemm(
    const u16* __restrict__ Ag, const u16* __restrict__ Wg,
    const float* __restrict__ bias, void* __restrict__ Cg,
    int N, int K, int Mbound, long astride, long wstride, long cstride) {
  __shared__ u16 As[128 * 64];
  __shared__ u16 Ws[128 * 64];
  const int z = blockIdx.z;
  const u16* A = Ag + (size_t)z * astride;
  const u16* W = Wg + (size_t)z * wstride;
  const int m0 = blockIdx.x * 128, n0 = blockIdx.y * 128;
  const int t = threadIdx.x, wave = t >> 6, lane = t & 63;
  const int fr = lane & 15, k8 = (lane >> 4) * 8;
  const int srow = lane >> 3, scol = (lane & 7) * 8;
  const int wm = wave >> 1, wn = wave & 1;
  f32x4 acc[4][4] = {};
  for (int kt = 0; kt < K; kt += 64) {
    #pragma unroll
    for (int i = 0; i < 4; ++i) {
      int slot = wave * 4 + i;
      gl16(A + (size_t)(m0 + slot * 8 + srow) * K + kt + scol, As + slot * 512);
      gl16(W + (size_t)(n0 + slot * 8 + srow) * K + kt + scol, Ws + slot * 512);
    }
    __syncthreads();
    short8 a[4][2], b[4][2];
    #pragma unroll
    for (int mi = 0; mi < 4; ++mi)
      #pragma unroll
      for (int c = 0; c < 2; ++c)
        a[mi][c] = *reinterpret_cast<const short8*>(
            As + (wm * 64 + mi * 16 + fr) * 64 + c * 32 + k8);
    #pragma unroll
    for (int ni = 0; ni < 4; ++ni)
      #pragma unroll
      for (int c = 0; c < 2; ++c)
        b[ni][c] = *reinterpret_cast<const short8*>(
            Ws + (wn * 64 + ni * 16 + fr) * 64 + c * 32 + k8);
    #pragma unroll
    for (int c = 0; c < 2; ++c)
      #pragma unroll
      for (int mi = 0; mi < 4; ++mi)
        #pragma unroll
        for (int ni = 0; ni < 4; ++ni)
          acc[mi][ni] = __builtin_amdgcn_mfma_f32_16x16x32_bf16(
              a[mi][c], b[ni][c], acc[mi][ni], 0, 0, 0);
    __syncthreads();
  }
  const int r0 = (lane >> 4) * 4;
  #pragma unroll
  for (int mi = 0; mi < 4; ++mi) {
    #pragma unroll
    for (int ni = 0; ni < 4; ++ni) {
      int col = n0 + wn * 64 + ni * 16 + fr;
      float bs = bias ? bias[col] : 0.f;
      #pragma unroll
      for (int i = 0; i < 4; ++i) {
        int row = m0 + wm * 64 + mi * 16 + r0 + i;
        if (row < Mbound) {
          float v = acc[mi][ni][i] + bs;
          if (MODE == 2) v = fmaxf(v, 0.f);
          size_t o = (size_t)z * cstride + (size_t)row * N + col;
          if (MODE == 0) ((float*)Cg)[o] = v;
          else           ((u16*)Cg)[o] = f2bf(v);
        }
      }
    }
  }
}

// ---------------- fused attention probabilities (MFMA) --------------------
// qkh rows: [q(512) || k(512)] bf16, row stride QKS_. Writes w2 bf16,
// per batch W2R_ x KP_ with zero pad cols. 1-D grid of NMT_*B_ blocks,
// XCD-chunk swizzled. avg kept in registers (33/thread) — no scratch.
__global__ __launch_bounds__(256) void k_attn_mfma(
    const u16* __restrict__ QK, const float* __restrict__ bias,
    u16* __restrict__ W2) {
  __shared__ float s[16][528];     // 33792 B -> 4 blocks/CU
  // bijective XCD-chunk swizzle: 1056 blocks, 1056/8 = 132 per XCD
  const int logical = (blockIdx.x & 7) * 132 + (blockIdx.x >> 3);
  const int b = logical / NMT_, lt = logical % NMT_;
  const int t = threadIdx.x;
  const int wave = t >> 6, lane = t & 63;
  const int fr = lane & 15, k8 = (lane >> 4) * 8;
  const int row = t >> 4, sub = t & 15;

  float avg[NMT_];
  #pragma unroll
  for (int j = 0; j < NMT_; ++j) avg[j] = 0.f;

  const u16* qrow  = QK + ((size_t)b * L_ + lt * 16 + fr) * QKS_;
  const u16* kbase = QK + (size_t)b * L_ * QKS_ + 512;

  const float scale = 0.125f;
  for (int h = 0; h < H_; ++h) {
    short8 qf0 = *reinterpret_cast<const short8*>(qrow + h * DH_ + k8);
    short8 qf1 = *reinterpret_cast<const short8*>(qrow + h * DH_ + 32 + k8);
    for (int mt = wave; mt < NMT_; mt += 4) {
      f32x4 acc = {0.f, 0.f, 0.f, 0.f};
      const u16* kr = kbase + (size_t)(mt * 16 + fr) * QKS_ + h * DH_;
      acc = __builtin_amdgcn_mfma_f32_16x16x32_bf16(
          qf0, *reinterpret_cast<const short8*>(kr + k8), acc, 0, 0, 0);
      acc = __builtin_amdgcn_mfma_f32_16x16x32_bf16(
          qf1, *reinterpret_cast<const short8*>(kr + 32 + k8), acc, 0, 0, 0);
      int m = mt * 16 + fr;
      #pragma unroll
      for (int i = 0; i < 4; ++i) {
        int r = (lane >> 4) * 4 + i;
        s[r][m] = (m < L_) ? acc[i] * scale : -INFINITY;
      }
    }
    __syncthreads();
    // row softmax over m; avg[j] += exp(s-mx)/sum (exp recomputed, no arrays)
    float mx = -INFINITY;
    #pragma unroll
    for (int j = 0; j < NMT_; ++j) mx = fmaxf(mx, s[row][sub + 16 * j]);
    #pragma unroll
    for (int off = 8; off >= 1; off >>= 1) mx = fmaxf(mx, __shfl_xor(mx, off));
    float sm = 0.f;
    #pragma unroll
    for (int j = 0; j < NMT_; ++j) sm += __expf(s[row][sub + 16 * j] - mx);
    #pragma unroll
    for (int off = 8; off >= 1; off >>= 1) sm += __shfl_xor(sm, off);
    float inv = 1.f / sm;
    #pragma unroll
    for (int j = 0; j < NMT_; ++j)
      avg[j] += __expf(s[row][sub + 16 * j] - mx) * inv;
    __syncthreads();
  }

  // second softmax: v = avg/H + bias[l,:]
  int l = lt * 16 + row;
  if (l < L_) {
    const float* brow = bias + (size_t)l * L_;
    float mx = -INFINITY;
    #pragma unroll
    for (int j = 0; j < NMT_; ++j) {
      int m = sub + 16 * j;
      float v = (m < L_) ? avg[j] * (1.f / H_) + brow[m] : -INFINITY;
      avg[j] = v;
      mx = fmaxf(mx, v);
    }
    #pragma unroll
    for (int off = 8; off >= 1; off >>= 1) mx = fmaxf(mx, __shfl_xor(mx, off));
    float sm = 0.f;
    #pragma unroll
    for (int j = 0; j < NMT_; ++j) sm += __expf(avg[j] - mx);
    #pragma unroll
    for (int off = 8; off >= 1; off >>= 1) sm += __shfl_xor(sm, off);
    float inv = 1.f / sm;
    u16* w2row = W2 + ((size_t)b * W2R_ + l) * KP_;
    #pragma unroll
    for (int j = 0; j < KP_ / 16; ++j) {   // 36, zero-pad tail
      int m = sub + 16 * j;
      float val = 0.f;
      if (j < NMT_ && m < L_) val = __expf(avg[j] - mx) * inv;
      w2row[m] = f2bf(val);
    }
  }
}

// ---------------- transpose src_bf16 (B,L,E) -> srcT (B,E,KP_) ------------
__global__ __launch_bounds__(256) void k_transpose(
    const u16* __restrict__ src, u16* __restrict__ dst) {
  __shared__ u16 T[32][34];
  const int b = blockIdx.z, e0 = blockIdx.x * 32, m0 = blockIdx.y * 32;
  const int t = threadIdx.x;
  const int c = t & 31, r = t >> 5;   // 8 rows/pass
  #pragma unroll
  for (int j = 0; j < 4; ++j) {
    int m = m0 + r + j * 8;
    T[r + j * 8][c] =
        (m < L_) ? src[((size_t)b * L_ + m) * E_ + e0 + c] : (u16)0;
  }
  __syncthreads();
  #pragma unroll
  for (int j = 0; j < 4; ++j) {
    int e = e0 + r + j * 8;
    dst[((size_t)b * E_ + e) * KP_ + m0 + c] = T[c][r + j * 8];
  }
}

// ---------------- out = LayerNorm(x + y) * w + b (fp32 + bf16) ------------
__global__ __launch_bounds__(256) void k_add_ln(
    const float* __restrict__ X, const float* __restrict__ Y,
    const float* __restrict__ w, const float* __restrict__ bb,
    float* __restrict__ out, u16* __restrict__ outh) {
  int row = blockIdx.x;
  int t = threadIdx.x;
  const float* xr = X + (size_t)row * E_;
  const float* yr = Y + (size_t)row * E_;
  __shared__ float red[4];
  float v0 = xr[t] + yr[t];
  float v1 = xr[t + 256] + yr[t + 256];
  float mean = blk_sum(v0 + v1, red) * (1.0f / E_);
  float d0 = v0 - mean, d1 = v1 - mean;
  float var = blk_sum(d0 * d0 + d1 * d1, red) * (1.0f / E_);
  float inv = rsqrtf(var + EPS_);
  float o0 = d0 * inv * w[t] + bb[t];
  float o1 = d1 * inv * w[t + 256] + bb[t + 256];
  float* orow = out + (size_t)row * E_;
  orow[t] = o0; orow[t + 256] = o1;
  u16* oh = outh + (size_t)row * E_;
  oh[t] = f2bf(o0); oh[t + 256] = f2bf(o1);
}

// ---------------- extract out = src[:, 0, :] ------------------------------
__global__ __launch_bounds__(256) void k_extract(
    const float* __restrict__ src, float* __restrict__ out) {
  int i = blockIdx.x * 256 + threadIdx.x;
  if (i >= B_ * E_) return;
  int b = i >> 9, e = i & (E_ - 1);
  out[i] = src[((size_t)b * L_) * E_ + e];
}

extern "C" void kernel_launch(void* const* d_in, const int* in_sizes, int n_in,
                              void* d_out, int out_size, void* d_ws, size_t ws_size,
                              hipStream_t stream) {
  const float* x        = (const float*)d_in[0];
  const float* tok_w    = (const float*)d_in[1];
  const float* tok_b    = (const float*)d_in[2];
  const float* bias     = (const float*)d_in[3];
  const float* in_proj_w= (const float*)d_in[4];
  const float* in_proj_b= (const float*)d_in[5];
  const float* fc1_w    = (const float*)d_in[6];
  const float* fc1_b    = (const float*)d_in[7];
  const float* fc2_w    = (const float*)d_in[8];
  const float* fc2_b    = (const float*)d_in[9];
  const float* ln1_w    = (const float*)d_in[10];
  const float* ln1_b    = (const float*)d_in[11];
  const float* ln2_w    = (const float*)d_in[12];
  const float* ln2_b    = (const float*)d_in[13];
  float* out = (float*)d_out;
  (void)in_sizes; (void)n_in; (void)out_size; (void)ws_size;

  float* ws = (float*)d_ws;
  const size_t ME  = (size_t)M_ * E_;        // 8,404,992 floats
  const size_t SLK = 65536;                  // 256KB slack (floats)
  float* src  = ws;                          // ME
  float* tmp  = src + ME;                    // ME
  u16*   srch = (u16*)(tmp + ME);            // M x E bf16 (+slack)
  u16*   qkh  = (u16*)((float*)srch + ME / 2 + SLK);   // M x 1024 bf16 (+slack)
  u16*   hid  = qkh;                                    // overlay (M x F bf16)
  u16*   w2   = (u16*)((float*)qkh + ME + SLK);         // B x W2R_ x KP_ bf16
  const size_t w2f = (size_t)B_ * W2R_ * KP_ / 2;
  u16*   srcT = (u16*)((float*)w2 + w2f);               // B x E x KP_ bf16
  const size_t sTf = (size_t)B_ * E_ * KP_ / 2;
  u16*   wqk  = (u16*)((float*)srcT + sTf);             // NL x 1024 x 512
  u16*   w1h  = wqk + (size_t)NL_ * F_ * E_;            // NL x 1024 x 512
  u16*   w2h  = w1h + (size_t)NL_ * F_ * E_;            // NL x 512 x 1024

  // weights -> bf16 (epl = 2^19)
  k_cvt<<<3072, 256, 0, stream>>>(in_proj_w, wqk, 524288L, 786432L);
  k_cvt<<<3072, 256, 0, stream>>>(fc1_w, w1h, 524288L, 524288L);
  k_cvt<<<3072, 256, 0, stream>>>(fc2_w, w2h, 524288L, 524288L);

  k_embed<<<dim3((B_ * L_ * E_ + 255) / 256), 256, 0, stream>>>(
      x, tok_w, tok_b, src, srch);

  const int MT = (M_ + 127) / 128;   // 129
  for (int i = 0; i < NL_; ++i) {
    // QK projection: [q||k] = src @ [wq;wk]^T + [bq;bk]  -> qkh bf16
    k_gemm<1><<<dim3(MT, 8, 1), 256, 0, stream>>>(
        srch, wqk + (size_t)i * F_ * E_, in_proj_b + (size_t)i * 3 * E_,
        qkh, 1024, 512, M_, 0, 0, 0);

    k_attn_mfma<<<dim3(NMT_ * B_), 256, 0, stream>>>(qkh, bias, w2);

    k_transpose<<<dim3(16, KP_ / 32, B_), 256, 0, stream>>>(srch, srcT);

    // attn_out = w2 @ src  (batched NT vs srcT), fp32 -> tmp
    k_gemm<0><<<dim3(5, 4, 32), 256, 0, stream>>>(
        w2, srcT, (const float*)nullptr, tmp, E_, KP_, L_,
        (long)W2R_ * KP_, (long)E_ * KP_, (long)L_ * E_);

    k_add_ln<<<M_, 256, 0, stream>>>(src, tmp,
        ln1_w + (size_t)i * E_, ln1_b + (size_t)i * E_, src, srch);

    k_gemm<2><<<dim3(MT, 8, 1), 256, 0, stream>>>(
        srch, w1h + (size_t)i * F_ * E_, fc1_b + (size_t)i * F_,
        hid, 1024, 512, M_, 0, 0, 0);

    k_gemm<0><<<dim3(MT, 4, 1), 256, 0, stream>>>(
        hid, w2h + (size_t)i * E_ * F_, fc2_b + (size_t)i * E_,
        tmp, 512, 1024, M_, 0, 0, 0);

    k_add_ln<<<M_, 256, 0, stream>>>(src, tmp,
        ln2_w + (size_t)i * E_, ln2_b + (size_t)i * E_, src, srch);
  }

  k_extract<<<dim3((B_ * E_ + 255) / 256), 256, 0, stream>>>(src, out);
}

// Round 7
// 2430.819 us; speedup vs baseline: 12.5405x; 1.0175x over previous
//
#include <hip/hip_runtime.h>
#include <hip/hip_bf16.h>
#include <math.h>

#define E_ 512
#define H_ 8
#define NL_ 6
#define F_ 1024
#define S_ 512
#define L_ 513
#define B_ 32
#define DH_ 64
#define M_ (B_*L_)      // 16416
#define EPS_ 1e-5f
#define NMT_ 33         // attn m-tiles (528/16)
#define KP_ 576         // padded K for attn_out gemm (multiple of 64)
#define W2R_ 640        // w2 rows alloc per batch (5 tiles of 128)
#define QKS_ 1024       // qkh row stride in ushorts (q||k)

typedef __attribute__((ext_vector_type(8))) short short8;
typedef __attribute__((ext_vector_type(4))) float f32x4;
typedef unsigned short u16;
typedef unsigned int u32;

__device__ __forceinline__ u16 f2bf(float f) {
  union { float f; unsigned u; } v; v.f = f;
  unsigned r = v.u + 0x7FFF + ((v.u >> 16) & 1);   // RNE
  return (u16)(r >> 16);
}

__device__ __forceinline__ void gl16(const void* g, void* l) {
  __builtin_amdgcn_global_load_lds(
      (const __attribute__((address_space(1))) u32*)g,
      (__attribute__((address_space(3))) u32*)l, 16, 0, 0);
}

// ---------------- block reduce (blockDim=256) -----------------------------
__device__ __forceinline__ float blk_sum(float v, float* red) {
  #pragma unroll
  for (int off = 32; off > 0; off >>= 1) v += __shfl_down(v, off);
  int wid = threadIdx.x >> 6;
  if ((threadIdx.x & 63) == 0) red[wid] = v;
  __syncthreads();
  if (threadIdx.x == 0) red[0] = (red[0] + red[1]) + (red[2] + red[3]);
  __syncthreads();
  float r = red[0];
  __syncthreads();
  return r;
}

// ---------------- weight fp32 -> bf16 (all layers) ------------------------
__global__ __launch_bounds__(256) void k_cvt(
    const float* __restrict__ srcp, u16* __restrict__ dst,
    long epl, long src_stride) {        // epl multiple of 4
  long idx = ((long)blockIdx.x * 256 + threadIdx.x) * 4;
  long layer = idx / epl;
  if (layer >= NL_) return;
  long j = idx - layer * epl;
  float4 v = *reinterpret_cast<const float4*>(srcp + layer * src_stride + j);
  ushort4 o;
  o.x = f2bf(v.x); o.y = f2bf(v.y); o.z = f2bf(v.z); o.w = f2bf(v.w);
  *reinterpret_cast<ushort4*>(dst + idx) = o;
}

// ---------------- embed: src = tok_w * x_num + tok_b (fp32 + bf16) --------
__global__ __launch_bounds__(256) void k_embed(
    const float* __restrict__ x, const float* __restrict__ tok_w,
    const float* __restrict__ tok_b, float* __restrict__ src,
    u16* __restrict__ srch) {
  int idx = blockIdx.x * 256 + threadIdx.x;
  if (idx >= B_ * L_ * E_) return;
  int e  = idx & (E_ - 1);
  int bl = idx >> 9;
  int l  = bl % L_;
  int b  = bl / L_;
  float xv = (l == 0) ? 1.0f : x[b * S_ + (l - 1)];
  float v = tok_w[l * E_ + e] * xv + tok_b[l * E_ + e];
  src[idx] = v;
  srch[idx] = f2bf(v);
}

// ---------------- unified bf16 MFMA GEMM: C = A @ W^T + bias --------------
// A: MxK bf16 row-major; W: NxK bf16 row-major (k-contig both).
// MODE 0: fp32 out; 1: bf16 out; 2: bf16 out + relu. Batched via blockIdx.z.
template<int MODE>
__global__ __launch_bounds__(256) void k_gemm(
    const u16* __restrict__ Ag, const u16* __restrict__ Wg,
    const float* __restrict__ bias, void* __restrict__ Cg,
    int N, int K, int Mbound, long astride, long wstride, long cstride) {
  __shared__ u16 As[128 * 64];
  __shared__ u16 Ws[128 * 64];
  const int z = blockIdx.z;
  const u16* A = Ag + (size_t)z * astride;
  const u16* W = Wg + (size_t)z * wstride;
  const int m0 = blockIdx.x * 128, n0 = blockIdx.y * 128;
  const int t = threadIdx.x, wave = t >> 6, lane = t & 63;
  const int fr = lane & 15, k8 = (lane >> 4) * 8;
  const int srow = lane >> 3, scol = (lane & 7) * 8;
  const int wm = wave >> 1, wn = wave & 1;
  f32x4 acc[4][4] = {};
  for (int kt = 0; kt < K; kt += 64) {
    #pragma unroll
    for (int i = 0; i < 4; ++i) {
      int slot = wave * 4 + i;
      gl16(A + (size_t)(m0 + slot * 8 + srow) * K + kt + scol, As + slot * 512);
      gl16(W + (size_t)(n0 + slot * 8 + srow) * K + kt + scol, Ws + slot * 512);
    }
    __syncthreads();
    short8 a[4][2], b[4][2];
    #pragma unroll
    for (int mi = 0; mi < 4; ++mi)
      #pragma unroll
      for (int c = 0; c < 2; ++c)
        a[mi][c] = *reinterpret_cast<const short8*>(
            As + (wm * 64 + mi * 16 + fr) * 64 + c * 32 + k8);
    #pragma unroll
    for (int ni = 0; ni < 4; ++ni)
      #pragma unroll
      for (int c = 0; c < 2; ++c)
        b[ni][c] = *reinterpret_cast<const short8*>(
            Ws + (wn * 64 + ni * 16 + fr) * 64 + c * 32 + k8);
    #pragma unroll
    for (int c = 0; c < 2; ++c)
      #pragma unroll
      for (int mi = 0; mi < 4; ++mi)
        #pragma unroll
        for (int ni = 0; ni < 4; ++ni)
          acc[mi][ni] = __builtin_amdgcn_mfma_f32_16x16x32_bf16(
              a[mi][c], b[ni][c], acc[mi][ni], 0, 0, 0);
    __syncthreads();
  }
  const int r0 = (lane >> 4) * 4;
  #pragma unroll
  for (int mi = 0; mi < 4; ++mi) {
    #pragma unroll
    for (int ni = 0; ni < 4; ++ni) {
      int col = n0 + wn * 64 + ni * 16 + fr;
      float bs = bias ? bias[col] : 0.f;
      #pragma unroll
      for (int i = 0; i < 4; ++i) {
        int row = m0 + wm * 64 + mi * 16 + r0 + i;
        if (row < Mbound) {
          float v = acc[mi][ni][i] + bs;
          if (MODE == 2) v = fmaxf(v, 0.f);
          size_t o = (size_t)z * cstride + (size_t)row * N + col;
          if (MODE == 0) ((float*)Cg)[o] = v;
          else           ((u16*)Cg)[o] = f2bf(v);
        }
      }
    }
  }
}

// ---------------- fused attention probabilities (MFMA) --------------------
// qkh rows: [q(512) || k(512)] bf16, row stride QKS_. Writes w2 bf16,
// per batch W2R_ x KP_ with zero pad cols. 1-D grid of NMT_*B_ blocks,
// XCD-chunk swizzled. 512 threads / 8 waves: short mt phases + deep TLP.
// e[] kept in regs (compile-time indexed -> no scratch).
__global__ __launch_bounds__(512) void k_attn_mfma(
    const u16* __restrict__ QK, const float* __restrict__ bias,
    u16* __restrict__ W2) {
  __shared__ float s[16][528];     // 33792 B
  // bijective XCD-chunk swizzle: 1056 blocks, 1056/8 = 132 per XCD
  const int logical = (blockIdx.x & 7) * 132 + (blockIdx.x >> 3);
  const int b = logical / NMT_, lt = logical % NMT_;
  const int t = threadIdx.x;
  const int wave = t >> 6, lane = t & 63;
  const int fr = lane & 15, k8 = (lane >> 4) * 8;
  const int row = t >> 5, sub = t & 31;   // 16 rows x 32 threads

  float avg[17];
  #pragma unroll
  for (int j = 0; j < 17; ++j) avg[j] = 0.f;

  const u16* qrow  = QK + ((size_t)b * L_ + lt * 16 + fr) * QKS_;
  const u16* kbase = QK + (size_t)b * L_ * QKS_ + 512;

  const float scale = 0.125f;
  for (int h = 0; h < H_; ++h) {
    short8 qf0 = *reinterpret_cast<const short8*>(qrow + h * DH_ + k8);
    short8 qf1 = *reinterpret_cast<const short8*>(qrow + h * DH_ + 32 + k8);
    #pragma unroll 2
    for (int mt = wave; mt < NMT_; mt += 8) {
      f32x4 acc = {0.f, 0.f, 0.f, 0.f};
      const u16* kr = kbase + (size_t)(mt * 16 + fr) * QKS_ + h * DH_;
      acc = __builtin_amdgcn_mfma_f32_16x16x32_bf16(
          qf0, *reinterpret_cast<const short8*>(kr + k8), acc, 0, 0, 0);
      acc = __builtin_amdgcn_mfma_f32_16x16x32_bf16(
          qf1, *reinterpret_cast<const short8*>(kr + 32 + k8), acc, 0, 0, 0);
      int m = mt * 16 + fr;
      #pragma unroll
      for (int i = 0; i < 4; ++i) {
        int r = (lane >> 4) * 4 + i;
        s[r][m] = (m < L_) ? acc[i] * scale : -INFINITY;
      }
    }
    __syncthreads();
    // row softmax over m (32 threads/row, 17-elem slices), e[] in regs
    float sv[17];
    #pragma unroll
    for (int j = 0; j < 17; ++j) {
      int m = sub + 32 * j;
      sv[j] = (m < 528) ? s[row][m] : -INFINITY;
    }
    float mx = -INFINITY;
    #pragma unroll
    for (int j = 0; j < 17; ++j) mx = fmaxf(mx, sv[j]);
    #pragma unroll
    for (int off = 16; off >= 1; off >>= 1) mx = fmaxf(mx, __shfl_xor(mx, off));
    float e[17];
    float sm = 0.f;
    #pragma unroll
    for (int j = 0; j < 17; ++j) { e[j] = __expf(sv[j] - mx); sm += e[j]; }
    #pragma unroll
    for (int off = 16; off >= 1; off >>= 1) sm += __shfl_xor(sm, off);
    float inv = 1.f / sm;
    #pragma unroll
    for (int j = 0; j < 17; ++j) avg[j] += e[j] * inv;
    __syncthreads();
  }

  // second softmax: v = avg/H + bias[l,:]
  int l = lt * 16 + row;
  if (l < L_) {
    const float* brow = bias + (size_t)l * L_;
    float mx = -INFINITY;
    #pragma unroll
    for (int j = 0; j < 17; ++j) {
      int m = sub + 32 * j;
      float v = (m < L_) ? avg[j] * (1.f / H_) + brow[m] : -INFINITY;
      avg[j] = v;
      mx = fmaxf(mx, v);
    }
    #pragma unroll
    for (int off = 16; off >= 1; off >>= 1) mx = fmaxf(mx, __shfl_xor(mx, off));
    float e[17];
    float sm = 0.f;
    #pragma unroll
    for (int j = 0; j < 17; ++j) { e[j] = __expf(avg[j] - mx); sm += e[j]; }
    #pragma unroll
    for (int off = 16; off >= 1; off >>= 1) sm += __shfl_xor(sm, off);
    float inv = 1.f / sm;
    u16* w2row = W2 + ((size_t)b * W2R_ + l) * KP_;
    #pragma unroll
    for (int j = 0; j < 18; ++j) {     // covers KP_=576 (zero pad tail)
      int m = sub + 32 * j;
      float val = 0.f;
      if (j < 17) { if (m < L_) val = e[j] * inv; }
      w2row[m] = f2bf(val);
    }
  }
}

// ---------------- transpose src_bf16 (B,L,E) -> srcT (B,E,KP_) ------------
__global__ __launch_bounds__(256) void k_transpose(
    const u16* __restrict__ src, u16* __restrict__ dst) {
  __shared__ u16 T[32][34];
  const int b = blockIdx.z, e0 = blockIdx.x * 32, m0 = blockIdx.y * 32;
  const int t = threadIdx.x;
  const int c = t & 31, r = t >> 5;   // 8 rows/pass
  #pragma unroll
  for (int j = 0; j < 4; ++j) {
    int m = m0 + r + j * 8;
    T[r + j * 8][c] =
        (m < L_) ? src[((size_t)b * L_ + m) * E_ + e0 + c] : (u16)0;
  }
  __syncthreads();
  #pragma unroll
  for (int j = 0; j < 4; ++j) {
    int e = e0 + r + j * 8;
    dst[((size_t)b * E_ + e) * KP_ + m0 + c] = T[c][r + j * 8];
  }
}

// ---------------- out = LayerNorm(x + y) * w + b (fp32 + bf16) ------------
__global__ __launch_bounds__(256) void k_add_ln(
    const float* __restrict__ X, const float* __restrict__ Y,
    const float* __restrict__ w, const float* __restrict__ bb,
    float* __restrict__ out, u16* __restrict__ outh) {
  int row = blockIdx.x;
  int t = threadIdx.x;
  const float* xr = X + (size_t)row * E_;
  const float* yr = Y + (size_t)row * E_;
  __shared__ float red[4];
  float v0 = xr[t] + yr[t];
  float v1 = xr[t + 256] + yr[t + 256];
  float mean = blk_sum(v0 + v1, red) * (1.0f / E_);
  float d0 = v0 - mean, d1 = v1 - mean;
  float var = blk_sum(d0 * d0 + d1 * d1, red) * (1.0f / E_);
  float inv = rsqrtf(var + EPS_);
  float o0 = d0 * inv * w[t] + bb[t];
  float o1 = d1 * inv * w[t + 256] + bb[t + 256];
  float* orow = out + (size_t)row * E_;
  orow[t] = o0; orow[t + 256] = o1;
  u16* oh = outh + (size_t)row * E_;
  oh[t] = f2bf(o0); oh[t + 256] = f2bf(o1);
}

// ---------------- extract out = src[:, 0, :] ------------------------------
__global__ __launch_bounds__(256) void k_extract(
    const float* __restrict__ src, float* __restrict__ out) {
  int i = blockIdx.x * 256 + threadIdx.x;
  if (i >= B_ * E_) return;
  int b = i >> 9, e = i & (E_ - 1);
  out[i] = src[((size_t)b * L_) * E_ + e];
}

extern "C" void kernel_launch(void* const* d_in, const int* in_sizes, int n_in,
                              void* d_out, int out_size, void* d_ws, size_t ws_size,
                              hipStream_t stream) {
  const float* x        = (const float*)d_in[0];
  const float* tok_w    = (const float*)d_in[1];
  const float* tok_b    = (const float*)d_in[2];
  const float* bias     = (const float*)d_in[3];
  const float* in_proj_w= (const float*)d_in[4];
  const float* in_proj_b= (const float*)d_in[5];
  const float* fc1_w    = (const float*)d_in[6];
  const float* fc1_b    = (const float*)d_in[7];
  const float* fc2_w    = (const float*)d_in[8];
  const float* fc2_b    = (const float*)d_in[9];
  const float* ln1_w    = (const float*)d_in[10];
  const float* ln1_b    = (const float*)d_in[11];
  const float* ln2_w    = (const float*)d_in[12];
  const float* ln2_b    = (const float*)d_in[13];
  float* out = (float*)d_out;
  (void)in_sizes; (void)n_in; (void)out_size; (void)ws_size;

  float* ws = (float*)d_ws;
  const size_t ME  = (size_t)M_ * E_;        // 8,404,992 floats
  const size_t SLK = 65536;                  // 256KB slack (floats)
  float* src  = ws;                          // ME
  float* tmp  = src + ME;                    // ME
  u16*   srch = (u16*)(tmp + ME);            // M x E bf16 (+slack)
  u16*   qkh  = (u16*)((float*)srch + ME / 2 + SLK);   // M x 1024 bf16 (+slack)
  u16*   hid  = qkh;                                    // overlay (M x F bf16)
  u16*   w2   = (u16*)((float*)qkh + ME + SLK);         // B x W2R_ x KP_ bf16
  const size_t w2f = (size_t)B_ * W2R_ * KP_ / 2;
  u16*   srcT = (u16*)((float*)w2 + w2f);               // B x E x KP_ bf16
  const size_t sTf = (size_t)B_ * E_ * KP_ / 2;
  u16*   wqk  = (u16*)((float*)srcT + sTf);             // NL x 1024 x 512
  u16*   w1h  = wqk + (size_t)NL_ * F_ * E_;            // NL x 1024 x 512
  u16*   w2h  = w1h + (size_t)NL_ * F_ * E_;            // NL x 512 x 1024

  // weights -> bf16 (epl = 2^19)
  k_cvt<<<3072, 256, 0, stream>>>(in_proj_w, wqk, 524288L, 786432L);
  k_cvt<<<3072, 256, 0, stream>>>(fc1_w, w1h, 524288L, 524288L);
  k_cvt<<<3072, 256, 0, stream>>>(fc2_w, w2h, 524288L, 524288L);

  k_embed<<<dim3((B_ * L_ * E_ + 255) / 256), 256, 0, stream>>>(
      x, tok_w, tok_b, src, srch);

  const int MT = (M_ + 127) / 128;   // 129
  for (int i = 0; i < NL_; ++i) {
    // QK projection: [q||k] = src @ [wq;wk]^T + [bq;bk]  -> qkh bf16
    k_gemm<1><<<dim3(MT, 8, 1), 256, 0, stream>>>(
        srch, wqk + (size_t)i * F_ * E_, in_proj_b + (size_t)i * 3 * E_,
        qkh, 1024, 512, M_, 0, 0, 0);

    k_attn_mfma<<<dim3(NMT_ * B_), 512, 0, stream>>>(qkh, bias, w2);

    k_transpose<<<dim3(16, KP_ / 32, B_), 256, 0, stream>>>(srch, srcT);

    // attn_out = w2 @ src  (batched NT vs srcT), fp32 -> tmp
    k_gemm<0><<<dim3(5, 4, 32), 256, 0, stream>>>(
        w2, srcT, (const float*)nullptr, tmp, E_, KP_, L_,
        (long)W2R_ * KP_, (long)E_ * KP_, (long)L_ * E_);

    k_add_ln<<<M_, 256, 0, stream>>>(src, tmp,
        ln1_w + (size_t)i * E_, ln1_b + (size_t)i * E_, src, srch);

    k_gemm<2><<<dim3(MT, 8, 1), 256, 0, stream>>>(
        srch, w1h + (size_t)i * F_ * E_, fc1_b + (size_t)i * F_,
        hid, 1024, 512, M_, 0, 0, 0);

    k_gemm<0><<<dim3(MT, 4, 1), 256, 0, stream>>>(
        hid, w2h + (size_t)i * E_ * F_, fc2_b + (size_t)i * E_,
        tmp, 512, 1024, M_, 0, 0, 0);

    k_add_ln<<<M_, 256, 0, stream>>>(src, tmp,
        ln2_w + (size_t)i * E_, ln2_b + (size_t)i * E_, src, srch);
  }

  k_extract<<<dim3((B_ * E_ + 255) / 256), 256, 0, stream>>>(src, out);
}